// Round 6
// baseline (57.545 us; speedup 1.0000x reference)
//
#include <hip/hip_runtime.h>

// Problem constants (from reference)
constexpr int N = 2;
constexpr int C = 20;
constexpr int H = 64;
constexpr int W = 2048;          // power of two -> wrap via & (W-1)
constexpr int HW = H * W;

constexpr int BLK   = 512;       // 8 waves: lanes 0-255 classes 0-9, 256-511 classes 10-19
constexpr int SITES = 256;       // w-sites per block
constexpr int NTAP  = 25;
constexpr int WITEMS = NTAP * SITES;   // 6400 weights per block

__global__ __launch_bounds__(BLK, 8)   // force VGPR<=64 -> 32 waves/CU
void lcl_xyz_kernel(const float* __restrict__ xyz,
                    const float* __restrict__ softmax,
                    const int* __restrict__ mask,
                    float* __restrict__ out) {
    __shared__ float sW[NTAP][SITES];  // weights, [tap][site] -> stride-1 across lanes

    const int t = threadIdx.x;

    // XCD-contiguous strip swizzle: XCD (bid%8) owns 128 consecutive work ids
    // -> 16 contiguous (n*64+h) rows per XCD L2.
    const int bid  = blockIdx.x;
    const int work = (bid & 7) * 128 + (bid >> 3);    // bijective over [0,1024)
    const int nh   = work >> 3;                        // n*64+h
    const int bw   = work & 7;
    const int n    = nh >> 6;
    const int h    = nh & 63;
    const int w0   = bw * SITES;

    const float* xb  = xyz + (size_t)(n * 3 + 0) * HW;
    const float* yb  = xyz + (size_t)(n * 3 + 1) * HW;
    const float* zb  = xyz + (size_t)(n * 3 + 2) * HW;
    const int*   mb  = mask + (size_t)n * HW;
    const float* smb = softmax + (size_t)n * C * HW;

    // ---- Cooperative weight phase: 6400 gaussian*mask*valid weights ----
    for (int k = 0; k < (WITEMS + BLK - 1) / BLK; ++k) {
        int it = t + BLK * k;
        if (it < WITEMS) {
            int tap = it >> 8;                 // 0..24
            int si  = it & (SITES - 1);        // site within block
            int r   = tap / 5;
            int j   = tap - 5 * r;
            int hh  = h - 2 + r;
            bool hv = (unsigned)hh < (unsigned)H;
            int ro  = min(max(hh, 0), H - 1) * W;
            int col = (w0 + si + j - 2) & (W - 1);
            int cc  = h * W + w0 + si;         // center offset

            float dx = xb[ro + col] - xb[cc];
            float dy = yb[ro + col] - yb[cc];
            float dz = zb[ro + col] - zb[cc];
            float g  = __expf(-0.5f * (dx * dx + dy * dy + dz * dz));
            sW[tap][si] = (hv && mb[ro + col]) ? g : 0.0f;
        }
    }
    __syncthreads();

    // ---- Per-thread setup: site, class range, weights -> registers ----
    const int s  = t & (SITES - 1);
    const int cb = (t >> 8) * 10;              // 0 or 10

    float w25[NTAP];
    #pragma unroll
    for (int tap = 0; tap < NTAP; ++tap) w25[tap] = sW[tap][s];

    int rowoff[5];
    #pragma unroll
    for (int r = 0; r < 5; ++r) rowoff[r] = min(max(h - 2 + r, 0), H - 1) * W;

    int col5[5];
    #pragma unroll
    for (int j = 0; j < 5; ++j) col5[j] = (w0 + s + j - 2) & (W - 1);

    // ---- Class loop: 25 coalesced L1-hit loads + 25 FMA per class ----
    float* ob = out + (size_t)n * C * HW + (size_t)h * W + w0 + s;

    for (int c = cb; c < cb + 10; ++c) {
        const float* sc = smb + (size_t)c * HW;
        float acc = 0.0f;
        #pragma unroll
        for (int r = 0; r < 5; ++r) {
            const float* p = sc + rowoff[r];
            #pragma unroll
            for (int j = 0; j < 5; ++j) {
                acc = fmaf(w25[r * 5 + j], p[col5[j]], acc);
            }
        }
        ob[(size_t)c * HW] = acc;
    }
}

extern "C" void kernel_launch(void* const* d_in, const int* in_sizes, int n_in,
                              void* d_out, int out_size, void* d_ws, size_t ws_size,
                              hipStream_t stream) {
    const float* xyz     = (const float*)d_in[0];
    const float* softmax = (const float*)d_in[1];
    const int*   mask    = (const int*)d_in[2];
    float*       out     = (float*)d_out;

    const int grid = N * H * (W / SITES);     // 2*64*8 = 1024 blocks
    lcl_xyz_kernel<<<grid, BLK, 0, stream>>>(xyz, softmax, mask, out);
}